// Round 13
// baseline (26.828 us; speedup 1.0000x reference)
//
#include <hip/hip_runtime.h>

#define BATCH  2048
#define NIN    128
#define NOUT   128
#define T      128
#define XLO    (-6.0f)
#define XRANGE 12.0f
#define NCHUNK 16
#define ILEN   8               // i's per chunk
#define JTILE  4               // j's per block
#define L2E    1.44269504088896340736f

typedef float v2f __attribute__((ext_vector_type(2)));
typedef unsigned int u32;

__device__ __forceinline__ v2f splat(float s) { v2f v; v.x = s; v.y = s; return v; }

// v2f silu with paired rcp: 2 exp + 1 rcp
__device__ __forceinline__ v2f silu2(v2f x) {
    float e0 = __builtin_amdgcn_exp2f(x.x * -L2E);
    float e1 = __builtin_amdgcn_exp2f(x.y * -L2E);
    float d0 = 1.0f + e0, d1 = 1.0f + e1;
    float rp = __builtin_amdgcn_rcpf(d0 * d1);
    v2f r; r.x = x.x * rp * d1; r.y = x.y * rp * d0;
    return r;
}

__device__ __forceinline__ void silu_pair(float& u, float& v) {
    float eu = __builtin_amdgcn_exp2f(u * -L2E);
    float ev = __builtin_amdgcn_exp2f(v * -L2E);
    float du = 1.0f + eu, dv = 1.0f + ev;
    float rp = __builtin_amdgcn_rcpf(du * dv);
    float su = u * rp * dv;
    float sv = v * rp * du;
    u = su; v = sv;
}

__device__ __forceinline__ float silu_f(float x) {
    float e = __builtin_amdgcn_exp2f(x * -L2E);
    return x * __builtin_amdgcn_rcpf(1.0f + e);
}

__device__ __forceinline__ u32 bf16rn(float v) {   // RN-even bf16 bits
    u32 b = __float_as_uint(v);
    return (b + 0x7fffu + ((b >> 16) & 1u)) >> 16;
}

// 1-5-5-1 subnet on a knot pair: returns s*y + r*x
__device__ __forceinline__ v2f net_v2(
    const float* __restrict__ w0, const float* __restrict__ b0,
    const float* __restrict__ w1, const float* __restrict__ b1,
    const float* __restrict__ w2, const float* __restrict__ b2a,
    const float* __restrict__ s,  const float* __restrict__ r,
    int nw, v2f xv)
{
    const int n5 = nw * 5, n25 = nw * 25;
    v2f a[5];
    #pragma unroll
    for (int k = 0; k < 5; ++k)
        a[k] = silu2(w0[n5 + k] * xv + splat(b0[n5 + k]));
    v2f h2[5];
    #pragma unroll
    for (int k = 0; k < 5; ++k) {
        v2f u = splat(b1[n5 + k]);
        #pragma unroll
        for (int l = 0; l < 5; ++l)
            u = w1[n25 + k * 5 + l] * a[l] + u;
        h2[k] = silu2(u);
    }
    v2f y = splat(b2a[nw]);
    #pragma unroll
    for (int l = 0; l < 5; ++l)
        y = w2[n5 + l] * h2[l] + y;
    return y * s[nw] + xv * r[nw];
}

// ---- fused: build 32 tables in LDS (2 per wave), then eval 4 j's, all b ----
__global__ __launch_bounds__(1024, 8) void kfused(
    const float* __restrict__ x,
    const float* __restrict__ w00, const float* __restrict__ b00,
    const float* __restrict__ w01, const float* __restrict__ b01,
    const float* __restrict__ w02, const float* __restrict__ b02,
    const float* __restrict__ s0,  const float* __restrict__ r0,
    float* __restrict__ hTs,
    float* __restrict__ out)
{
    __shared__ u32 tab[ILEN * T * JTILE];   // [ii][knot][jj] = 16 KB
    const int tid  = threadIdx.x;
    const int c    = blockIdx.x;            // i-chunk 0..15
    const int jg   = blockIdx.y;            // j-group 0..31
    const int j0   = jg * JTILE;
    const int i0   = c * ILEN;
    const int w    = tid >> 6;              // wave id 0..15
    const int lane = tid & 63;
    const int wi   = w & 7;                 // ii this wave builds
    const int wj   = (w >> 3) * 2;          // jj base this wave builds

    // zero out[] for klayer1's atomics (jg==0, c<2 blocks cover all 2048)
    if (jg == 0 && c < 2) out[c * 1024 + tid] = 0.0f;

    // ---------- phase 1: build; wave w builds table (ii=wi, jj=wj..wj+1) ----------
    const float h  = XRANGE / (float)(T - 1);
    const int   k2 = lane * 2;
    v2f xv;
    xv.x = XLO + (float)k2 * h;
    xv.y = XLO + (float)(k2 + 1) * h;

    #pragma unroll
    for (int jj = 0; jj < 2; ++jj) {
        int nw = (i0 + wi) * NOUT + (j0 + wj + jj);     // weight net index
        nw = __builtin_amdgcn_readfirstlane(nw);        // force SGPR path

        v2f g = net_v2(w00, b00, w01, b01, w02, b02, s0, r0, nw, xv);

        float ynext = __shfl_down(g.x, 1, 64);          // y at knot k2+2
        u32 pk0 = (bf16rn(g.x) << 16) | bf16rn(g.y - g.x);
        u32 pk1 = (bf16rn(g.y) << 16) | bf16rn(ynext - g.y);  // lane63 dy unused

        const int base = (wi * T + k2) * JTILE + wj + jj;
        tab[base]         = pk0;
        tab[base + JTILE] = pk1;
    }
    __syncthreads();

    // ---------- phase 2: eval, 2 passes x 1024 threads over batch ----------
    const float invh = (float)(T - 1) / XRANGE;
    const float tofs = -XLO * invh;

    #pragma unroll
    for (int p = 0; p < 2; ++p) {
        const int b = p * 1024 + tid;
        const float4* xp = (const float4*)(x + (size_t)b * NIN + i0);
        float4 xq[2];
        xq[0] = xp[0]; xq[1] = xp[1];

        float acc0 = 0.0f, acc1 = 0.0f, acc2 = 0.0f, acc3 = 0.0f;

        #pragma unroll
        for (int q = 0; q < 2; ++q) {
            #pragma unroll
            for (int e = 0; e < 4; ++e) {
                const int ii = q * 4 + e;
                const float xval = (e == 0) ? xq[q].x : (e == 1) ? xq[q].y
                                 : (e == 2) ? xq[q].z : xq[q].w;
                float t = fmaf(xval, invh, tofs);
                t = fminf(fmaxf(t, 0.0f), (float)(T - 2));  // v_med3 clamp
                const int   idx = (int)t;
                const float f   = t - (float)idx;
                const uint4 qq = *(const uint4*)&tab[(ii * T + idx) * JTILE];
                acc0 = fmaf(f, __uint_as_float(qq.x << 16), acc0 + __uint_as_float(qq.x & 0xffff0000u));
                acc1 = fmaf(f, __uint_as_float(qq.y << 16), acc1 + __uint_as_float(qq.y & 0xffff0000u));
                acc2 = fmaf(f, __uint_as_float(qq.z << 16), acc2 + __uint_as_float(qq.z & 0xffff0000u));
                acc3 = fmaf(f, __uint_as_float(qq.w << 16), acc3 + __uint_as_float(qq.w & 0xffff0000u));
            }
        }

        hTs[((size_t)c * NOUT + j0 + 0) * BATCH + b] = acc0;
        hTs[((size_t)c * NOUT + j0 + 1) * BATCH + b] = acc1;
        hTs[((size_t)c * NOUT + j0 + 2) * BATCH + b] = acc2;
        hTs[((size_t)c * NOUT + j0 + 3) * BATCH + b] = acc3;
    }
}

// -------- layer 1 (second KAN layer): analytic, sums partial slices --------
#define IPB 2
__global__ __launch_bounds__(64) void klayer1(
    const float* __restrict__ hTs,
    const float* __restrict__ w0, const float* __restrict__ bb0,
    const float* __restrict__ w1, const float* __restrict__ bb1,
    const float* __restrict__ w2, const float* __restrict__ bb2,
    const float* __restrict__ s,  const float* __restrict__ r,
    float* __restrict__ out)
{
    const int b  = blockIdx.x * 64 + threadIdx.x;
    const int i0 = blockIdx.y * IPB;

    float acc = 0.0f;

    #pragma unroll
    for (int ii = 0; ii < IPB; ++ii) {
        const int i  = i0 + ii;
        const int i5 = i * 5, i25 = i * 25;

        float xv = 0.0f;
        #pragma unroll
        for (int cc = 0; cc < NCHUNK; ++cc)
            xv += hTs[((size_t)cc * NOUT + i) * BATCH + b];

        float a[5];
        #pragma unroll
        for (int k = 0; k < 5; ++k)
            a[k] = fmaf(w0[i5 + k], xv, bb0[i5 + k]);
        silu_pair(a[0], a[1]);
        silu_pair(a[2], a[3]);
        a[4] = silu_f(a[4]);

        float h2[5];
        #pragma unroll
        for (int k = 0; k < 5; ++k) {
            float u = bb1[i5 + k];
            #pragma unroll
            for (int l = 0; l < 5; ++l)
                u = fmaf(w1[i25 + k * 5 + l], a[l], u);
            h2[k] = u;
        }
        silu_pair(h2[0], h2[1]);
        silu_pair(h2[2], h2[3]);
        h2[4] = silu_f(h2[4]);

        float y = bb2[i];
        #pragma unroll
        for (int l = 0; l < 5; ++l)
            y = fmaf(w2[i5 + l], h2[l], y);

        acc = fmaf(y, s[i], fmaf(xv, r[i], acc));
    }

    atomicAdd(&out[b], acc);
}

extern "C" void kernel_launch(void* const* d_in, const int* in_sizes, int n_in,
                              void* d_out, int out_size, void* d_ws, size_t ws_size,
                              hipStream_t stream) {
    const float* x    = (const float*)d_in[0];
    const float* w0_0 = (const float*)d_in[1];
    const float* b0_0 = (const float*)d_in[2];
    const float* w0_1 = (const float*)d_in[3];
    const float* b0_1 = (const float*)d_in[4];
    const float* w0_2 = (const float*)d_in[5];
    const float* b0_2 = (const float*)d_in[6];
    const float* s0   = (const float*)d_in[7];
    const float* r0   = (const float*)d_in[8];
    const float* w1_0 = (const float*)d_in[9];
    const float* b1_0 = (const float*)d_in[10];
    const float* w1_1 = (const float*)d_in[11];
    const float* b1_1 = (const float*)d_in[12];
    const float* w1_2 = (const float*)d_in[13];
    const float* b1_2 = (const float*)d_in[14];
    const float* s1   = (const float*)d_in[15];
    const float* r1   = (const float*)d_in[16];

    float* out = (float*)d_out;
    float* hTs = (float*)d_ws;            // [NCHUNK][NOUT][BATCH] = 16 MB

    kfused<<<dim3(NCHUNK, NOUT / JTILE), 1024, 0, stream>>>(
        x, w0_0, b0_0, w0_1, b0_1, w0_2, b0_2, s0, r0, hTs, out);

    klayer1<<<dim3(BATCH / 64, NIN / IPB), 64, 0, stream>>>(
        hTs, w1_0, b1_0, w1_1, b1_1, w1_2, b1_2, s1, r1, out);
}

// Round 14
// 24.366 us; speedup vs baseline: 1.1011x; 1.1011x over previous
//
#include <hip/hip_runtime.h>

#define BATCH  2048
#define NIN    128
#define NOUT   128
#define T      128
#define XLO    (-6.0f)
#define XRANGE 12.0f
#define NCHUNK 8
#define ILEN   16              // i's per chunk = waves per block
#define JTILE  4               // j's per block
#define L2E    1.44269504088896340736f

typedef float v2f __attribute__((ext_vector_type(2)));
typedef unsigned int u32;

__device__ __forceinline__ v2f splat(float s) { v2f v; v.x = s; v.y = s; return v; }

// v2f silu with paired rcp: 2 exp + 1 rcp
__device__ __forceinline__ v2f silu2(v2f x) {
    float e0 = __builtin_amdgcn_exp2f(x.x * -L2E);
    float e1 = __builtin_amdgcn_exp2f(x.y * -L2E);
    float d0 = 1.0f + e0, d1 = 1.0f + e1;
    float rp = __builtin_amdgcn_rcpf(d0 * d1);
    v2f r; r.x = x.x * rp * d1; r.y = x.y * rp * d0;
    return r;
}

__device__ __forceinline__ void silu_pair(float& u, float& v) {
    float eu = __builtin_amdgcn_exp2f(u * -L2E);
    float ev = __builtin_amdgcn_exp2f(v * -L2E);
    float du = 1.0f + eu, dv = 1.0f + ev;
    float rp = __builtin_amdgcn_rcpf(du * dv);
    float su = u * rp * dv;
    float sv = v * rp * du;
    u = su; v = sv;
}

__device__ __forceinline__ float silu_f(float x) {
    float e = __builtin_amdgcn_exp2f(x * -L2E);
    return x * __builtin_amdgcn_rcpf(1.0f + e);
}

__device__ __forceinline__ u32 bf16rn(float v) {   // RN-even bf16 bits
    u32 b = __float_as_uint(v);
    return (b + 0x7fffu + ((b >> 16) & 1u)) >> 16;
}

// 1-5-5-1 subnet on a knot pair: returns s*y + r*x
__device__ __forceinline__ v2f net_v2(
    const float* __restrict__ w0, const float* __restrict__ b0,
    const float* __restrict__ w1, const float* __restrict__ b1,
    const float* __restrict__ w2, const float* __restrict__ b2a,
    const float* __restrict__ s,  const float* __restrict__ r,
    int nw, v2f xv)
{
    const int n5 = nw * 5, n25 = nw * 25;
    v2f a[5];
    #pragma unroll
    for (int k = 0; k < 5; ++k)
        a[k] = silu2(w0[n5 + k] * xv + splat(b0[n5 + k]));
    v2f h2[5];
    #pragma unroll
    for (int k = 0; k < 5; ++k) {
        v2f u = splat(b1[n5 + k]);
        #pragma unroll
        for (int l = 0; l < 5; ++l)
            u = w1[n25 + k * 5 + l] * a[l] + u;
        h2[k] = silu2(u);
    }
    v2f y = splat(b2a[nw]);
    #pragma unroll
    for (int l = 0; l < 5; ++l)
        y = w2[n5 + l] * h2[l] + y;
    return y * s[nw] + xv * r[nw];
}

// ---- fused: build 64 tables in LDS (1 ii per wave), then eval 4 j's, all b ----
// tab layout [jj][ii][knot]: bank = idx % 32 -> near-conflict-free random gather
__global__ __launch_bounds__(1024) void kfused(
    const float* __restrict__ x,
    const float* __restrict__ w00, const float* __restrict__ b00,
    const float* __restrict__ w01, const float* __restrict__ b01,
    const float* __restrict__ w02, const float* __restrict__ b02,
    const float* __restrict__ s0,  const float* __restrict__ r0,
    float* __restrict__ hTs,
    float* __restrict__ out)
{
    __shared__ u32 tab[JTILE * ILEN * T];   // [jj][ii][knot] = 32 KB
    const int tid  = threadIdx.x;
    const int c    = blockIdx.x;            // i-chunk 0..7
    const int jg   = blockIdx.y;            // j-group 0..31
    const int j0   = jg * JTILE;
    const int i0   = c * ILEN;
    const int w    = tid >> 6;              // wave id 0..15 = ii (wave-uniform)
    const int lane = tid & 63;

    // zero out[] for klayer1's atomics (jg==0, c<2 blocks cover all 2048)
    if (jg == 0 && c < 2) out[c * 1024 + tid] = 0.0f;

    // ---------- phase 1: build; wave w builds ii=w for jj=0..3 ----------
    const float h  = XRANGE / (float)(T - 1);
    const int   k2 = lane * 2;
    v2f xv;
    xv.x = XLO + (float)k2 * h;
    xv.y = XLO + (float)(k2 + 1) * h;

    #pragma unroll
    for (int jj = 0; jj < JTILE; ++jj) {
        int nw = (i0 + w) * NOUT + (j0 + jj);           // weight net index
        nw = __builtin_amdgcn_readfirstlane(nw);        // force SGPR path

        v2f g = net_v2(w00, b00, w01, b01, w02, b02, s0, r0, nw, xv);

        float ynext = __shfl_down(g.x, 1, 64);          // y at knot k2+2
        u32 pk0 = (bf16rn(g.x) << 16) | bf16rn(g.y - g.x);
        u32 pk1 = (bf16rn(g.y) << 16) | bf16rn(ynext - g.y);  // lane63 dy unused

        uint2 pr; pr.x = pk0; pr.y = pk1;
        *(uint2*)&tab[(jj * ILEN + w) * T + k2] = pr;   // 8B-aligned b64 write
    }
    __syncthreads();

    // ---------- phase 2: eval, 2 passes x 1024 threads over batch ----------
    const float invh = (float)(T - 1) / XRANGE;
    const float tofs = -XLO * invh;

    #pragma unroll
    for (int p = 0; p < 2; ++p) {
        const int b = p * 1024 + tid;
        const float4* xp = (const float4*)(x + (size_t)b * NIN + i0);
        float4 xq[4];
        xq[0] = xp[0]; xq[1] = xp[1]; xq[2] = xp[2]; xq[3] = xp[3];

        float acc0 = 0.0f, acc1 = 0.0f, acc2 = 0.0f, acc3 = 0.0f;

        #pragma unroll
        for (int q = 0; q < 4; ++q) {
            #pragma unroll
            for (int e = 0; e < 4; ++e) {
                const int ii = q * 4 + e;
                const float xval = (e == 0) ? xq[q].x : (e == 1) ? xq[q].y
                                 : (e == 2) ? xq[q].z : xq[q].w;
                float t = fmaf(xval, invh, tofs);
                t = fminf(fmaxf(t, 0.0f), (float)(T - 2));  // v_med3 clamp
                const int   idx = (int)t;
                const float f   = t - (float)idx;
                // 4 b32 gathers, one vaddr + 8KB immediate offsets
                const u32 u0 = tab[(0 * ILEN + ii) * T + idx];
                const u32 u1 = tab[(1 * ILEN + ii) * T + idx];
                const u32 u2 = tab[(2 * ILEN + ii) * T + idx];
                const u32 u3 = tab[(3 * ILEN + ii) * T + idx];
                acc0 = fmaf(f, __uint_as_float(u0 << 16), acc0 + __uint_as_float(u0 & 0xffff0000u));
                acc1 = fmaf(f, __uint_as_float(u1 << 16), acc1 + __uint_as_float(u1 & 0xffff0000u));
                acc2 = fmaf(f, __uint_as_float(u2 << 16), acc2 + __uint_as_float(u2 & 0xffff0000u));
                acc3 = fmaf(f, __uint_as_float(u3 << 16), acc3 + __uint_as_float(u3 & 0xffff0000u));
            }
        }

        hTs[((size_t)c * NOUT + j0 + 0) * BATCH + b] = acc0;
        hTs[((size_t)c * NOUT + j0 + 1) * BATCH + b] = acc1;
        hTs[((size_t)c * NOUT + j0 + 2) * BATCH + b] = acc2;
        hTs[((size_t)c * NOUT + j0 + 3) * BATCH + b] = acc3;
    }
}

// -------- layer 1 (second KAN layer): analytic, sums partial slices --------
#define IPB 2
__global__ __launch_bounds__(64) void klayer1(
    const float* __restrict__ hTs,
    const float* __restrict__ w0, const float* __restrict__ bb0,
    const float* __restrict__ w1, const float* __restrict__ bb1,
    const float* __restrict__ w2, const float* __restrict__ bb2,
    const float* __restrict__ s,  const float* __restrict__ r,
    float* __restrict__ out)
{
    const int b  = blockIdx.x * 64 + threadIdx.x;
    const int i0 = blockIdx.y * IPB;

    float acc = 0.0f;

    #pragma unroll
    for (int ii = 0; ii < IPB; ++ii) {
        const int i  = i0 + ii;
        const int i5 = i * 5, i25 = i * 25;

        float xv = 0.0f;
        #pragma unroll
        for (int cc = 0; cc < NCHUNK; ++cc)
            xv += hTs[((size_t)cc * NOUT + i) * BATCH + b];

        float a[5];
        #pragma unroll
        for (int k = 0; k < 5; ++k)
            a[k] = fmaf(w0[i5 + k], xv, bb0[i5 + k]);
        silu_pair(a[0], a[1]);
        silu_pair(a[2], a[3]);
        a[4] = silu_f(a[4]);

        float h2[5];
        #pragma unroll
        for (int k = 0; k < 5; ++k) {
            float u = bb1[i5 + k];
            #pragma unroll
            for (int l = 0; l < 5; ++l)
                u = fmaf(w1[i25 + k * 5 + l], a[l], u);
            h2[k] = u;
        }
        silu_pair(h2[0], h2[1]);
        silu_pair(h2[2], h2[3]);
        h2[4] = silu_f(h2[4]);

        float y = bb2[i];
        #pragma unroll
        for (int l = 0; l < 5; ++l)
            y = fmaf(w2[i5 + l], h2[l], y);

        acc = fmaf(y, s[i], fmaf(xv, r[i], acc));
    }

    atomicAdd(&out[b], acc);
}

extern "C" void kernel_launch(void* const* d_in, const int* in_sizes, int n_in,
                              void* d_out, int out_size, void* d_ws, size_t ws_size,
                              hipStream_t stream) {
    const float* x    = (const float*)d_in[0];
    const float* w0_0 = (const float*)d_in[1];
    const float* b0_0 = (const float*)d_in[2];
    const float* w0_1 = (const float*)d_in[3];
    const float* b0_1 = (const float*)d_in[4];
    const float* w0_2 = (const float*)d_in[5];
    const float* b0_2 = (const float*)d_in[6];
    const float* s0   = (const float*)d_in[7];
    const float* r0   = (const float*)d_in[8];
    const float* w1_0 = (const float*)d_in[9];
    const float* b1_0 = (const float*)d_in[10];
    const float* w1_1 = (const float*)d_in[11];
    const float* b1_1 = (const float*)d_in[12];
    const float* w1_2 = (const float*)d_in[13];
    const float* b1_2 = (const float*)d_in[14];
    const float* s1   = (const float*)d_in[15];
    const float* r1   = (const float*)d_in[16];

    float* out = (float*)d_out;
    float* hTs = (float*)d_ws;            // [NCHUNK][NOUT][BATCH] = 8 MB

    kfused<<<dim3(NCHUNK, NOUT / JTILE), 1024, 0, stream>>>(
        x, w0_0, b0_0, w0_1, b0_1, w0_2, b0_2, s0, r0, hTs, out);

    klayer1<<<dim3(BATCH / 64, NIN / IPB), 64, 0, stream>>>(
        hTs, w1_0, b1_0, w1_1, b1_1, w1_2, b1_2, s1, r1, out);
}